// Round 1
// baseline (889.037 us; speedup 1.0000x reference)
//
#include <hip/hip_runtime.h>

typedef __bf16 bf16x8 __attribute__((ext_vector_type(8)));
typedef float f32x4 __attribute__((ext_vector_type(4)));

static constexpr int TOKS = 43520;   // B * LQ
static constexpr int LQN  = 21760;

__device__ __forceinline__ unsigned short f2bf(float f) {
  union { float f; unsigned u; } v; v.f = f;
  return (unsigned short)((v.u + 0x7fffu + ((v.u >> 16) & 1u)) >> 16);
}
__device__ __forceinline__ float bf2f(unsigned short b) {
  union { unsigned u; float f; } v; v.u = ((unsigned)b) << 16; return v.f;
}

// ---- weight transpose+convert: Wt[n*K+k] = bf16(W[k*N+n])
__global__ __launch_bounds__(256) void wt_kernel(const float* __restrict__ W,
                                                 unsigned short* __restrict__ Wt,
                                                 int K, int N) {
  int idx = blockIdx.x * 256 + threadIdx.x;
  if (idx >= K * N) return;
  int k = idx / N, n = idx - k * N;
  Wt[n * K + k] = f2bf(W[idx]);
}

// ---- prep: srcb = bf16(src); qb = bf16(src+pos)
__global__ __launch_bounds__(256) void prep_kernel(const float4* __restrict__ src,
                                                   const float4* __restrict__ pos,
                                                   ushort4* __restrict__ srcb,
                                                   ushort4* __restrict__ qb) {
  int i = blockIdx.x * 256 + threadIdx.x;
  float4 s = src[i], p = pos[i];
  srcb[i] = make_ushort4(f2bf(s.x), f2bf(s.y), f2bf(s.z), f2bf(s.w));
  qb[i]   = make_ushort4(f2bf(s.x + p.x), f2bf(s.y + p.y), f2bf(s.z + p.z), f2bf(s.w + p.w));
}

// ---- GEMM: C[M,N] = A[M,K] @ Bt[N,K]^T + bias
// outop: 0 = f32 store, 1 = bf16 store, 2 = relu -> bf16 store
__global__ __launch_bounds__(256) void gemm_bt(const unsigned short* __restrict__ A,
                                               const unsigned short* __restrict__ Bt,
                                               const float* __restrict__ bias,
                                               void* __restrict__ Cp,
                                               int N, int K, int outop) {
  __shared__ unsigned short As[128][40];   // +8 pad: 16B-aligned rows, 2-way bank alias (free)
  __shared__ unsigned short Bs[128][40];
  const int t = threadIdx.x;
  const int bm = blockIdx.x, bn = blockIdx.y;
  const int wave = t >> 6, lane = t & 63;
  const int wm = (wave & 1) << 6, wn = (wave >> 1) << 6;
  const int lr = lane & 15, lq = lane >> 4;
  const int row0 = t >> 2, cb0 = (t & 3) * 8;
  const int row1 = row0 + 64;
  f32x4 acc[4][4] = {};

  const size_t abase = (size_t)bm * 128 * K;
  const size_t bbase = (size_t)bn * 128 * K;
  for (int k0 = 0; k0 < K; k0 += 32) {
    __syncthreads();
    *(uint4*)&As[row0][cb0] = *(const uint4*)&A[abase + (size_t)row0 * K + k0 + cb0];
    *(uint4*)&As[row1][cb0] = *(const uint4*)&A[abase + (size_t)row1 * K + k0 + cb0];
    *(uint4*)&Bs[row0][cb0] = *(const uint4*)&Bt[bbase + (size_t)row0 * K + k0 + cb0];
    *(uint4*)&Bs[row1][cb0] = *(const uint4*)&Bt[bbase + (size_t)row1 * K + k0 + cb0];
    __syncthreads();
    bf16x8 af[4], bfr[4];
#pragma unroll
    for (int i = 0; i < 4; i++) af[i] = *(const bf16x8*)&As[wm + i * 16 + lr][lq * 8];
#pragma unroll
    for (int j = 0; j < 4; j++) bfr[j] = *(const bf16x8*)&Bs[wn + j * 16 + lr][lq * 8];
#pragma unroll
    for (int i = 0; i < 4; i++)
#pragma unroll
      for (int j = 0; j < 4; j++)
        acc[i][j] = __builtin_amdgcn_mfma_f32_16x16x32_bf16(af[i], bfr[j], acc[i][j], 0, 0, 0);
  }
  // C/D mapping (m89/m91): col = lane&15, row = (lane>>4)*4 + reg
  const int rb = bm * 128 + wm + lq * 4;
  const int cbase = bn * 128 + wn + lr;
#pragma unroll
  for (int j = 0; j < 4; j++) {
    const int col = cbase + j * 16;
    const float bv = bias[col];
#pragma unroll
    for (int i = 0; i < 4; i++) {
#pragma unroll
      for (int r = 0; r < 4; r++) {
        float v = acc[i][j][r] + bv;
        size_t o = (size_t)(rb + i * 16 + r) * N + col;
        if (outop == 0) ((float*)Cp)[o] = v;
        else if (outop == 1) ((unsigned short*)Cp)[o] = f2bf(v);
        else ((unsigned short*)Cp)[o] = f2bf(fmaxf(v, 0.f));
      }
    }
  }
}

// ---- deformable attention: softmax(16) + 16-point bilinear gather per (token, head)
// block = one token (256 threads); thread t: head = t>>5, dim = t&31
__global__ __launch_bounds__(256) void deform_kernel(const unsigned short* __restrict__ valb,
                                                     const unsigned short* __restrict__ offb,
                                                     const unsigned short* __restrict__ logitb,
                                                     const float* __restrict__ refp,
                                                     unsigned short* __restrict__ outb) {
  const int tok = blockIdx.x;
  const int t = threadIdx.x;
  const int h = t >> 5, d = t & 31;
  const int b = tok / LQN;
  const unsigned short* lg = logitb + (size_t)tok * 128 + h * 16;
  float w[16];
  float mx = -1e30f;
#pragma unroll
  for (int p = 0; p < 16; p++) { w[p] = bf2f(lg[p]); mx = fmaxf(mx, w[p]); }
  float s = 0.f;
#pragma unroll
  for (int p = 0; p < 16; p++) { w[p] = __expf(w[p] - mx); s += w[p]; }
  const float inv = 1.f / s;
  const unsigned short* of = offb + (size_t)tok * 256 + h * 32;
  const float* rp = refp + (size_t)tok * 8;
  const int SD[4] = {128, 64, 32, 16};
  const int ST[4] = {0, 16384, 20480, 21504};
  float acc = 0.f;
#pragma unroll
  for (int l = 0; l < 4; l++) {
    const int S = SD[l];
    const float Sf = (float)S;
    const unsigned short* vb = valb + ((size_t)(b * LQN + ST[l])) * 256 + h * 32 + d;
    const float rx = rp[l * 2 + 0] * Sf - 0.5f;
    const float ry = rp[l * 2 + 1] * Sf - 0.5f;
#pragma unroll
    for (int p = 0; p < 4; p++) {
      float x = rx + bf2f(of[l * 8 + p * 2 + 0]);
      float y = ry + bf2f(of[l * 8 + p * 2 + 1]);
      float aw = w[l * 4 + p] * inv;
      float x0f = floorf(x), y0f = floorf(y);
      int x0 = (int)x0f, y0 = (int)y0f;
      float fx = x - x0f, fy = y - y0f;
      float s00 = (1.f - fx) * (1.f - fy), s10 = fx * (1.f - fy);
      float s01 = (1.f - fx) * fy,         s11 = fx * fy;
      bool xin0 = (x0 >= 0) & (x0 < S), xin1 = (x0 + 1 >= 0) & (x0 + 1 < S);
      bool yin0 = (y0 >= 0) & (y0 < S), yin1 = (y0 + 1 >= 0) & (y0 + 1 < S);
      float sv = 0.f;
      if (yin0) {
        int rbase = y0 * S;
        if (xin0) sv += s00 * bf2f(vb[(size_t)(rbase + x0) * 256]);
        if (xin1) sv += s10 * bf2f(vb[(size_t)(rbase + x0 + 1) * 256]);
      }
      if (yin1) {
        int rbase = (y0 + 1) * S;
        if (xin0) sv += s01 * bf2f(vb[(size_t)(rbase + x0) * 256]);
        if (xin1) sv += s11 * bf2f(vb[(size_t)(rbase + x0 + 1) * 256]);
      }
      acc += aw * sv;
    }
  }
  outb[(size_t)tok * 256 + t] = f2bf(acc);
}

// ---- fused residual + layernorm; one wave per token row (64 lanes x float4)
// out: fp32; outb (optional): bf16 copy
__global__ __launch_bounds__(256) void ln_kernel(const float4* __restrict__ xa,
                                                 const float4* __restrict__ xb,
                                                 const float* __restrict__ g,
                                                 const float* __restrict__ beta,
                                                 float4* __restrict__ out,
                                                 ushort4* __restrict__ outb) {
  const int wv = blockIdx.x * 4 + (threadIdx.x >> 6);
  const int lane = threadIdx.x & 63;
  const size_t idx = (size_t)wv * 64 + lane;
  float4 a = xa[idx], c = xb[idx];
  float x0 = a.x + c.x, x1 = a.y + c.y, x2 = a.z + c.z, x3 = a.w + c.w;
  float sum = x0 + x1 + x2 + x3;
#pragma unroll
  for (int o = 32; o >= 1; o >>= 1) sum += __shfl_xor(sum, o, 64);
  const float mu = sum * (1.f / 256.f);
  float d0 = x0 - mu, d1 = x1 - mu, d2 = x2 - mu, d3 = x3 - mu;
  float ss = d0 * d0 + d1 * d1 + d2 * d2 + d3 * d3;
#pragma unroll
  for (int o = 32; o >= 1; o >>= 1) ss += __shfl_xor(ss, o, 64);
  const float rs = rsqrtf(ss * (1.f / 256.f) + 1e-5f);
  float4 gg = ((const float4*)g)[lane], bb = ((const float4*)beta)[lane];
  float4 y;
  y.x = d0 * rs * gg.x + bb.x;
  y.y = d1 * rs * gg.y + bb.y;
  y.z = d2 * rs * gg.z + bb.z;
  y.w = d3 * rs * gg.w + bb.w;
  out[idx] = y;
  if (outb) outb[idx] = make_ushort4(f2bf(y.x), f2bf(y.y), f2bf(y.z), f2bf(y.w));
}

extern "C" void kernel_launch(void* const* d_in, const int* in_sizes, int n_in,
                              void* d_out, int out_size, void* d_ws, size_t ws_size,
                              hipStream_t stream) {
  (void)in_sizes; (void)n_in; (void)out_size; (void)ws_size;
  const float* src    = (const float*)d_in[0];
  const float* pos    = (const float*)d_in[1];
  const float* refp   = (const float*)d_in[2];
  const float* W_off  = (const float*)d_in[3];
  const float* b_off  = (const float*)d_in[4];
  const float* W_attn = (const float*)d_in[5];
  const float* b_attn = (const float*)d_in[6];
  const float* W_val  = (const float*)d_in[7];
  const float* b_val  = (const float*)d_in[8];
  const float* W_out  = (const float*)d_in[9];
  const float* b_out  = (const float*)d_in[10];
  const float* ln1_g  = (const float*)d_in[11];
  const float* ln1_b  = (const float*)d_in[12];
  const float* W1     = (const float*)d_in[13];
  const float* b1     = (const float*)d_in[14];
  const float* W2     = (const float*)d_in[15];
  const float* b2     = (const float*)d_in[16];
  const float* ln2_g  = (const float*)d_in[17];
  const float* ln2_b  = (const float*)d_in[18];

  char* ws = (char*)d_ws;
  // bf16 transposed weights pool (N x K each)
  unsigned short* Wt_val  = (unsigned short*)ws;
  unsigned short* Wt_off  = Wt_val + 65536;
  unsigned short* Wt_attn = Wt_off + 65536;
  unsigned short* Wt_out  = Wt_attn + 32768;
  unsigned short* Wt_1    = Wt_out + 65536;
  unsigned short* Wt_2    = Wt_1 + 262144;
  const size_t WPOOL = 2u * 1024 * 1024;

  const size_t SZ_bf  = (size_t)TOKS * 256 * 2;   // 22,282,240 B
  const size_t SZ_bfh = (size_t)TOKS * 128 * 2;   // 11,141,120 B
  const size_t SZ_f   = (size_t)TOKS * 256 * 4;   // 44,564,480 B

  unsigned short* srcb   = (unsigned short*)(ws + WPOOL);
  unsigned short* qb     = (unsigned short*)(ws + WPOOL + SZ_bf);
  unsigned short* valb   = (unsigned short*)(ws + WPOOL + 2 * SZ_bf);
  unsigned short* offb   = (unsigned short*)(ws + WPOOL + 3 * SZ_bf);
  unsigned short* logitb = (unsigned short*)(ws + WPOOL + 4 * SZ_bf);
  float*          h_f    = (float*)(ws + WPOOL + 4 * SZ_bf + SZ_bfh);
  unsigned short* hb     = (unsigned short*)(ws + WPOOL + 4 * SZ_bf + SZ_bfh + SZ_f);
  // aliases (lifetime-disjoint):
  unsigned short* attnoutb = srcb;        // src_bf16 dead after value GEMM
  float*          C3       = (float*)qb;  // spans qb+valb (both dead by out-proj)
  float*          C5       = (float*)qb;  // C3 dead after LN1
  unsigned short* h_bf     = offb;        // off dead after deform kernel

  // 1. weight transpose+convert (tiny)
  wt_kernel<<<256, 256, 0, stream>>>(W_val, Wt_val, 256, 256);
  wt_kernel<<<256, 256, 0, stream>>>(W_off, Wt_off, 256, 256);
  wt_kernel<<<128, 256, 0, stream>>>(W_attn, Wt_attn, 256, 128);
  wt_kernel<<<256, 256, 0, stream>>>(W_out, Wt_out, 256, 256);
  wt_kernel<<<1024, 256, 0, stream>>>(W1, Wt_1, 256, 1024);
  wt_kernel<<<1024, 256, 0, stream>>>(W2, Wt_2, 1024, 256);

  // 2. prep: src->bf16, query = src+pos -> bf16
  prep_kernel<<<10880, 256, 0, stream>>>((const float4*)src, (const float4*)pos,
                                         (ushort4*)srcb, (ushort4*)qb);

  // 3. projections
  gemm_bt<<<dim3(340, 2), 256, 0, stream>>>(srcb, Wt_val, b_val, valb, 256, 256, 1);
  gemm_bt<<<dim3(340, 2), 256, 0, stream>>>(qb, Wt_off, b_off, offb, 256, 256, 1);
  gemm_bt<<<dim3(340, 1), 256, 0, stream>>>(qb, Wt_attn, b_attn, logitb, 128, 256, 1);

  // 4. deformable attention gather
  deform_kernel<<<TOKS, 256, 0, stream>>>(valb, offb, logitb, refp, attnoutb);

  // 5. output projection + residual + LN1
  gemm_bt<<<dim3(340, 2), 256, 0, stream>>>(attnoutb, Wt_out, b_out, C3, 256, 256, 0);
  ln_kernel<<<10880, 256, 0, stream>>>((const float4*)src, (const float4*)C3,
                                       ln1_g, ln1_b, (float4*)h_f, (ushort4*)h_bf);

  // 6. FFN
  gemm_bt<<<dim3(340, 8), 256, 0, stream>>>(h_bf, Wt_1, b1, hb, 1024, 256, 2);
  gemm_bt<<<dim3(340, 2), 256, 0, stream>>>(hb, Wt_2, b2, C5, 256, 1024, 0);

  // 7. residual + LN2 -> out
  ln_kernel<<<10880, 256, 0, stream>>>((const float4*)h_f, (const float4*)C5,
                                       ln2_g, ln2_b, (float4*)d_out, (ushort4*)nullptr);
}

// Round 2
// 536.060 us; speedup vs baseline: 1.6585x; 1.6585x over previous
//
#include <hip/hip_runtime.h>

typedef __bf16 bf16x8 __attribute__((ext_vector_type(8)));
typedef float f32x4 __attribute__((ext_vector_type(4)));

static constexpr int TOKS = 43520;   // B * LQ
static constexpr int LQN  = 21760;

__device__ __forceinline__ unsigned short f2bf(float f) {
  union { float f; unsigned u; } v; v.f = f;
  return (unsigned short)((v.u + 0x7fffu + ((v.u >> 16) & 1u)) >> 16);
}
__device__ __forceinline__ float bf2f(unsigned short b) {
  union { unsigned u; float f; } v; v.u = ((unsigned)b) << 16; return v.f;
}

// ---- weight transpose+convert: Wt[n*K+k] = bf16(W[k*N+n])
__global__ __launch_bounds__(256) void wt_kernel(const float* __restrict__ W,
                                                 unsigned short* __restrict__ Wt,
                                                 int K, int N) {
  int idx = blockIdx.x * 256 + threadIdx.x;
  if (idx >= K * N) return;
  int k = idx / N, n = idx - k * N;
  Wt[n * K + k] = f2bf(W[idx]);
}

// ---- prep: srcb = bf16(src); qb = bf16(src+pos)
__global__ __launch_bounds__(256) void prep_kernel(const float4* __restrict__ src,
                                                   const float4* __restrict__ pos,
                                                   ushort4* __restrict__ srcb,
                                                   ushort4* __restrict__ qb) {
  int i = blockIdx.x * 256 + threadIdx.x;
  float4 s = src[i], p = pos[i];
  srcb[i] = make_ushort4(f2bf(s.x), f2bf(s.y), f2bf(s.z), f2bf(s.w));
  qb[i]   = make_ushort4(f2bf(s.x + p.x), f2bf(s.y + p.y), f2bf(s.z + p.z), f2bf(s.w + p.w));
}

// ---- GEMM: C[M,N] = A[M,K] @ Bt[N,K]^T + bias
// outop: 0 = f32 store, 1 = bf16 store, 2 = relu -> bf16 store
__global__ __launch_bounds__(256) void gemm_bt(const unsigned short* __restrict__ A,
                                               const unsigned short* __restrict__ Bt,
                                               const float* __restrict__ bias,
                                               void* __restrict__ Cp,
                                               int N, int K, int outop) {
  __shared__ unsigned short As[128][40];   // +8 pad: 16B-aligned rows, 2-way bank alias (free)
  __shared__ unsigned short Bs[128][40];
  const int t = threadIdx.x;
  const int bm = blockIdx.x, bn = blockIdx.y;
  const int wave = t >> 6, lane = t & 63;
  const int wm = (wave & 1) << 6, wn = (wave >> 1) << 6;
  const int lr = lane & 15, lq = lane >> 4;
  const int row0 = t >> 2, cb0 = (t & 3) * 8;
  const int row1 = row0 + 64;
  f32x4 acc[4][4] = {};

  const size_t abase = (size_t)bm * 128 * K;
  const size_t bbase = (size_t)bn * 128 * K;
  for (int k0 = 0; k0 < K; k0 += 32) {
    __syncthreads();
    *(uint4*)&As[row0][cb0] = *(const uint4*)&A[abase + (size_t)row0 * K + k0 + cb0];
    *(uint4*)&As[row1][cb0] = *(const uint4*)&A[abase + (size_t)row1 * K + k0 + cb0];
    *(uint4*)&Bs[row0][cb0] = *(const uint4*)&Bt[bbase + (size_t)row0 * K + k0 + cb0];
    *(uint4*)&Bs[row1][cb0] = *(const uint4*)&Bt[bbase + (size_t)row1 * K + k0 + cb0];
    __syncthreads();
    bf16x8 af[4], bfr[4];
#pragma unroll
    for (int i = 0; i < 4; i++) af[i] = *(const bf16x8*)&As[wm + i * 16 + lr][lq * 8];
#pragma unroll
    for (int j = 0; j < 4; j++) bfr[j] = *(const bf16x8*)&Bs[wn + j * 16 + lr][lq * 8];
#pragma unroll
    for (int i = 0; i < 4; i++)
#pragma unroll
      for (int j = 0; j < 4; j++)
        acc[i][j] = __builtin_amdgcn_mfma_f32_16x16x32_bf16(af[i], bfr[j], acc[i][j], 0, 0, 0);
  }
  // C/D mapping (m89/m91): col = lane&15, row = (lane>>4)*4 + reg
  const int rb = bm * 128 + wm + lq * 4;
  const int cbase = bn * 128 + wn + lr;
#pragma unroll
  for (int j = 0; j < 4; j++) {
    const int col = cbase + j * 16;
    const float bv = bias[col];
#pragma unroll
    for (int i = 0; i < 4; i++) {
#pragma unroll
      for (int r = 0; r < 4; r++) {
        float v = acc[i][j][r] + bv;
        size_t o = (size_t)(rb + i * 16 + r) * N + col;
        if (outop == 0) ((float*)Cp)[o] = v;
        else if (outop == 1) ((unsigned short*)Cp)[o] = f2bf(v);
        else ((unsigned short*)Cp)[o] = f2bf(fmaxf(v, 0.f));
      }
    }
  }
}

// ---- bf16x8 (uint4) fused unpack+FMA into fp32 acc
__device__ __forceinline__ void fma8(uint4 v, float w, float* a) {
  const unsigned uu[4] = {v.x, v.y, v.z, v.w};
#pragma unroll
  for (int i = 0; i < 4; i++) {
    union { unsigned u; float f; } lo, hi;
    lo.u = uu[i] << 16;
    hi.u = uu[i] & 0xffff0000u;
    a[2 * i]     += w * lo.f;
    a[2 * i + 1] += w * hi.f;
  }
}

// ---- deformable attention, two-phase:
// phase 1: 64 threads, one per (token,head): softmax + sample positions -> LDS
// phase 2: 256 threads = 8 tok x 8 head x 4 dim-chunks(8 dims, 16B loads)
__global__ __launch_bounds__(256) void deform_kernel(const unsigned short* __restrict__ valb,
                                                     const unsigned short* __restrict__ offb,
                                                     const unsigned short* __restrict__ logitb,
                                                     const float* __restrict__ refp,
                                                     unsigned short* __restrict__ outb) {
  __shared__ float4 sP[8][8][17];   // (x, y, attn_weight, pad); [17] spreads LDS banks
  const int t = threadIdx.x;
  const int tok0 = blockIdx.x * 8;
  const int SD[4] = {128, 64, 32, 16};

  if (t < 64) {
    const int g = t >> 3, h = t & 7;
    const int tok = tok0 + g;
    // 16 logits = 32 B
    const unsigned short* lg = logitb + (size_t)tok * 128 + h * 16;
    uint4 lv0 = ((const uint4*)lg)[0];
    uint4 lv1 = ((const uint4*)lg)[1];
    const unsigned lw[8] = {lv0.x, lv0.y, lv0.z, lv0.w, lv1.x, lv1.y, lv1.z, lv1.w};
    float w[16];
#pragma unroll
    for (int i = 0; i < 8; i++) {
      union { unsigned u; float f; } lo, hi;
      lo.u = lw[i] << 16; hi.u = lw[i] & 0xffff0000u;
      w[2 * i] = lo.f; w[2 * i + 1] = hi.f;
    }
    float mx = -1e30f;
#pragma unroll
    for (int i = 0; i < 16; i++) mx = fmaxf(mx, w[i]);
    float s = 0.f;
#pragma unroll
    for (int i = 0; i < 16; i++) { w[i] = __expf(w[i] - mx); s += w[i]; }
    const float inv = 1.f / s;
    // 32 offsets = 64 B
    const unsigned short* of = offb + (size_t)tok * 256 + h * 32;
    uint4 o0 = ((const uint4*)of)[0], o1 = ((const uint4*)of)[1];
    uint4 o2 = ((const uint4*)of)[2], o3 = ((const uint4*)of)[3];
    const unsigned ow[16] = {o0.x, o0.y, o0.z, o0.w, o1.x, o1.y, o1.z, o1.w,
                             o2.x, o2.y, o2.z, o2.w, o3.x, o3.y, o3.z, o3.w};
    float off[32];
#pragma unroll
    for (int i = 0; i < 16; i++) {
      union { unsigned u; float f; } lo, hi;
      lo.u = ow[i] << 16; hi.u = ow[i] & 0xffff0000u;
      off[2 * i] = lo.f; off[2 * i + 1] = hi.f;
    }
    const float* rp = refp + (size_t)tok * 8;
#pragma unroll
    for (int l = 0; l < 4; l++) {
      const float Sf = (float)SD[l];
      const float rx = rp[l * 2 + 0] * Sf - 0.5f;
      const float ry = rp[l * 2 + 1] * Sf - 0.5f;
#pragma unroll
      for (int p = 0; p < 4; p++) {
        const int idx = l * 4 + p;
        sP[g][h][idx] = make_float4(rx + off[l * 8 + p * 2 + 0],
                                    ry + off[l * 8 + p * 2 + 1],
                                    w[idx] * inv, 0.f);
      }
    }
  }
  __syncthreads();

  const int g = t >> 5, h = (t >> 2) & 7, dc = t & 3;
  const int tok = tok0 + g;
  const int b = tok / LQN;
  float acc[8] = {0.f, 0.f, 0.f, 0.f, 0.f, 0.f, 0.f, 0.f};
  const int ST[4] = {0, 16384, 20480, 21504};
#pragma unroll
  for (int l = 0; l < 4; l++) {
    const int S = SD[l];
    const unsigned short* vb = valb + ((size_t)(b * LQN + ST[l])) * 256 + h * 32 + dc * 8;
#pragma unroll
    for (int p = 0; p < 4; p++) {
      float4 P = sP[g][h][l * 4 + p];
      const float x = P.x, y = P.y, aw = P.z;
      const float x0f = floorf(x), y0f = floorf(y);
      const int x0 = (int)x0f, y0 = (int)y0f;
      const float fx = x - x0f, fy = y - y0f;
      const bool xin0 = (x0 >= 0) & (x0 < S), xin1 = (x0 + 1 >= 0) & (x0 + 1 < S);
      const bool yin0 = (y0 >= 0) & (y0 < S), yin1 = (y0 + 1 >= 0) & (y0 + 1 < S);
      const float w00 = aw * (1.f - fx) * (1.f - fy) * (float)(xin0 & yin0);
      const float w10 = aw * fx * (1.f - fy)         * (float)(xin1 & yin0);
      const float w01 = aw * (1.f - fx) * fy         * (float)(xin0 & yin1);
      const float w11 = aw * fx * fy                 * (float)(xin1 & yin1);
      const int xc0 = min(max(x0, 0), S - 1), xc1 = min(max(x0 + 1, 0), S - 1);
      const int yc0 = min(max(y0, 0), S - 1), yc1 = min(max(y0 + 1, 0), S - 1);
      const unsigned short* r0 = vb + (size_t)(yc0 * S) * 256;
      const unsigned short* r1 = vb + (size_t)(yc1 * S) * 256;
      uint4 v00 = *(const uint4*)(r0 + (size_t)xc0 * 256);
      uint4 v10 = *(const uint4*)(r0 + (size_t)xc1 * 256);
      uint4 v01 = *(const uint4*)(r1 + (size_t)xc0 * 256);
      uint4 v11 = *(const uint4*)(r1 + (size_t)xc1 * 256);
      fma8(v00, w00, acc);
      fma8(v10, w10, acc);
      fma8(v01, w01, acc);
      fma8(v11, w11, acc);
    }
  }
  unsigned o[4];
#pragma unroll
  for (int i = 0; i < 4; i++)
    o[i] = (unsigned)f2bf(acc[2 * i]) | ((unsigned)f2bf(acc[2 * i + 1]) << 16);
  *(uint4*)(outb + (size_t)tok * 256 + h * 32 + dc * 8) = make_uint4(o[0], o[1], o[2], o[3]);
}

// ---- fused residual + layernorm; one wave per token row (64 lanes x float4)
// out: fp32; outb (optional): bf16 copy
__global__ __launch_bounds__(256) void ln_kernel(const float4* __restrict__ xa,
                                                 const float4* __restrict__ xb,
                                                 const float* __restrict__ g,
                                                 const float* __restrict__ beta,
                                                 float4* __restrict__ out,
                                                 ushort4* __restrict__ outb) {
  const int wv = blockIdx.x * 4 + (threadIdx.x >> 6);
  const int lane = threadIdx.x & 63;
  const size_t idx = (size_t)wv * 64 + lane;
  float4 a = xa[idx], c = xb[idx];
  float x0 = a.x + c.x, x1 = a.y + c.y, x2 = a.z + c.z, x3 = a.w + c.w;
  float sum = x0 + x1 + x2 + x3;
#pragma unroll
  for (int o = 32; o >= 1; o >>= 1) sum += __shfl_xor(sum, o, 64);
  const float mu = sum * (1.f / 256.f);
  float d0 = x0 - mu, d1 = x1 - mu, d2 = x2 - mu, d3 = x3 - mu;
  float ss = d0 * d0 + d1 * d1 + d2 * d2 + d3 * d3;
#pragma unroll
  for (int o = 32; o >= 1; o >>= 1) ss += __shfl_xor(ss, o, 64);
  const float rs = rsqrtf(ss * (1.f / 256.f) + 1e-5f);
  float4 gg = ((const float4*)g)[lane], bb = ((const float4*)beta)[lane];
  float4 y;
  y.x = d0 * rs * gg.x + bb.x;
  y.y = d1 * rs * gg.y + bb.y;
  y.z = d2 * rs * gg.z + bb.z;
  y.w = d3 * rs * gg.w + bb.w;
  out[idx] = y;
  if (outb) outb[idx] = make_ushort4(f2bf(y.x), f2bf(y.y), f2bf(y.z), f2bf(y.w));
}

extern "C" void kernel_launch(void* const* d_in, const int* in_sizes, int n_in,
                              void* d_out, int out_size, void* d_ws, size_t ws_size,
                              hipStream_t stream) {
  (void)in_sizes; (void)n_in; (void)out_size; (void)ws_size;
  const float* src    = (const float*)d_in[0];
  const float* pos    = (const float*)d_in[1];
  const float* refp   = (const float*)d_in[2];
  const float* W_off  = (const float*)d_in[3];
  const float* b_off  = (const float*)d_in[4];
  const float* W_attn = (const float*)d_in[5];
  const float* b_attn = (const float*)d_in[6];
  const float* W_val  = (const float*)d_in[7];
  const float* b_val  = (const float*)d_in[8];
  const float* W_out  = (const float*)d_in[9];
  const float* b_out  = (const float*)d_in[10];
  const float* ln1_g  = (const float*)d_in[11];
  const float* ln1_b  = (const float*)d_in[12];
  const float* W1     = (const float*)d_in[13];
  const float* b1     = (const float*)d_in[14];
  const float* W2     = (const float*)d_in[15];
  const float* b2     = (const float*)d_in[16];
  const float* ln2_g  = (const float*)d_in[17];
  const float* ln2_b  = (const float*)d_in[18];

  char* ws = (char*)d_ws;
  // bf16 transposed weights pool (N x K each)
  unsigned short* Wt_val  = (unsigned short*)ws;
  unsigned short* Wt_off  = Wt_val + 65536;
  unsigned short* Wt_attn = Wt_off + 65536;
  unsigned short* Wt_out  = Wt_attn + 32768;
  unsigned short* Wt_1    = Wt_out + 65536;
  unsigned short* Wt_2    = Wt_1 + 262144;
  const size_t WPOOL = 2u * 1024 * 1024;

  const size_t SZ_bf  = (size_t)TOKS * 256 * 2;   // 22,282,240 B
  const size_t SZ_bfh = (size_t)TOKS * 128 * 2;   // 11,141,120 B
  const size_t SZ_f   = (size_t)TOKS * 256 * 4;   // 44,564,480 B

  unsigned short* srcb   = (unsigned short*)(ws + WPOOL);
  unsigned short* qb     = (unsigned short*)(ws + WPOOL + SZ_bf);
  unsigned short* valb   = (unsigned short*)(ws + WPOOL + 2 * SZ_bf);
  unsigned short* offb   = (unsigned short*)(ws + WPOOL + 3 * SZ_bf);
  unsigned short* logitb = (unsigned short*)(ws + WPOOL + 4 * SZ_bf);
  float*          h_f    = (float*)(ws + WPOOL + 4 * SZ_bf + SZ_bfh);
  unsigned short* hb     = (unsigned short*)(ws + WPOOL + 4 * SZ_bf + SZ_bfh + SZ_f);
  // aliases (lifetime-disjoint):
  unsigned short* attnoutb = srcb;        // src_bf16 dead after value GEMM
  float*          C3       = (float*)qb;  // spans qb+valb (both dead by out-proj)
  float*          C5       = (float*)qb;  // C3 dead after LN1
  unsigned short* h_bf     = offb;        // off dead after deform kernel

  // 1. weight transpose+convert (tiny)
  wt_kernel<<<256, 256, 0, stream>>>(W_val, Wt_val, 256, 256);
  wt_kernel<<<256, 256, 0, stream>>>(W_off, Wt_off, 256, 256);
  wt_kernel<<<128, 256, 0, stream>>>(W_attn, Wt_attn, 256, 128);
  wt_kernel<<<256, 256, 0, stream>>>(W_out, Wt_out, 256, 256);
  wt_kernel<<<1024, 256, 0, stream>>>(W1, Wt_1, 256, 1024);
  wt_kernel<<<1024, 256, 0, stream>>>(W2, Wt_2, 1024, 256);

  // 2. prep: src->bf16, query = src+pos -> bf16
  prep_kernel<<<10880, 256, 0, stream>>>((const float4*)src, (const float4*)pos,
                                         (ushort4*)srcb, (ushort4*)qb);

  // 3. projections
  gemm_bt<<<dim3(340, 2), 256, 0, stream>>>(srcb, Wt_val, b_val, valb, 256, 256, 1);
  gemm_bt<<<dim3(340, 2), 256, 0, stream>>>(qb, Wt_off, b_off, offb, 256, 256, 1);
  gemm_bt<<<dim3(340, 1), 256, 0, stream>>>(qb, Wt_attn, b_attn, logitb, 128, 256, 1);

  // 4. deformable attention gather (8 tokens per block)
  deform_kernel<<<TOKS / 8, 256, 0, stream>>>(valb, offb, logitb, refp, attnoutb);

  // 5. output projection + residual + LN1
  gemm_bt<<<dim3(340, 2), 256, 0, stream>>>(attnoutb, Wt_out, b_out, C3, 256, 256, 0);
  ln_kernel<<<10880, 256, 0, stream>>>((const float4*)src, (const float4*)C3,
                                       ln1_g, ln1_b, (float4*)h_f, (ushort4*)h_bf);

  // 6. FFN
  gemm_bt<<<dim3(340, 8), 256, 0, stream>>>(h_bf, Wt_1, b1, hb, 1024, 256, 2);
  gemm_bt<<<dim3(340, 2), 256, 0, stream>>>(hb, Wt_2, b2, C5, 256, 1024, 0);

  // 7. residual + LN2 -> out
  ln_kernel<<<10880, 256, 0, stream>>>((const float4*)h_f, (const float4*)C5,
                                       ln2_g, ln2_b, (float4*)d_out, (ushort4*)nullptr);
}